// Round 3
// baseline (375.620 us; speedup 1.0000x reference)
//
#include <hip/hip_runtime.h>
#include <stdint.h>
#include <stddef.h>

static constexpr int NB = 2;       // batch
static constexpr int SS = 2048;    // seq
static constexpr int DDim = 1024;  // model dim
static constexpr int NH = 16;      // heads
static constexpr size_t BSD = (size_t)NB * SS * DDim;  // 4194304
static constexpr size_t DDn = (size_t)DDim * DDim;     // 1048576

typedef __attribute__((ext_vector_type(4))) float f32x4;
typedef __attribute__((ext_vector_type(8))) short bf16x8;

// exp2-folded constants: softmax uses exp2f(logit*SCL2 + mask*MSK2)
static constexpr float SCL2 = 0.125f * 1.4426950408889634f;
static constexpr float MSK2 = -1.4426950408889634e9f;

__device__ __forceinline__ short f2bf(float f) {
  union { float f; unsigned u; } v; v.f = f;
  unsigned r = v.u + 0x7FFFu + ((v.u >> 16) & 1u);
  return (short)(r >> 16);
}

__device__ __forceinline__ void gload_lds16(const void* src, void* dst) {
  __builtin_amdgcn_global_load_lds(
      (const __attribute__((address_space(1))) void*)src,
      (__attribute__((address_space(3))) void*)dst, 16, 0, 0);
}

// ---------------- fp32 -> bf16 convert (8 elems/thread) ----------------
__global__ void cvt_k(const float* __restrict__ in, short* __restrict__ out, int n8) {
  int i = blockIdx.x * 256 + threadIdx.x;
  if (i >= n8) return;
  const f32x4* p = (const f32x4*)in + (size_t)i * 2;
  f32x4 a = p[0], c = p[1];
  bf16x8 o;
  o[0] = f2bf(a[0]); o[1] = f2bf(a[1]); o[2] = f2bf(a[2]); o[3] = f2bf(a[3]);
  o[4] = f2bf(c[0]); o[5] = f2bf(c[1]); o[6] = f2bf(c[2]); o[7] = f2bf(c[3]);
  ((bf16x8*)out)[i] = o;
}

// ---------------- 128x128 bf16 C=A*B^T GEMM, double-buffered 2-phase ----------------
// MODE 0: split-heads bf16 [B,H,S,64]; MODE 1: V^T bf16 [B,H,64,S]; MODE 2: fp32 [M,N]
template <int MODE>
__global__ __launch_bounds__(256, 2) void gemm128(
    const short* __restrict__ A, const short* __restrict__ Bm,
    const float* __restrict__ bias, void* __restrict__ outp, int N, int ld, int nk) {
  __shared__ short la[2][4096], lb[2][4096];
  const int tid = threadIdx.x, wid = tid >> 6, lane = tid & 63;
  const int bM = blockIdx.y * 128, bN = blockIdx.x * 128;
  const int ar = lane & 15, ak = (lane >> 4) * 8;
  const int srow = lane >> 2, scol = (lane & 3) * 8;
  const int wr = wid >> 1, wc = wid & 1;
  f32x4 acc[4][4];
#pragma unroll
  for (int m = 0; m < 4; ++m)
#pragma unroll
    for (int n = 0; n < 4; ++n) acc[m][n] = (f32x4){0.f, 0.f, 0.f, 0.f};

  auto stage = [&](int kt, int bb) {
    const int k0 = kt * 32;
#pragma unroll
    for (int c = 0; c < 2; ++c) {
      int chunk = c * 4 + wid;
      gload_lds16(A + (size_t)(bM + chunk * 16 + srow) * ld + k0 + scol, &la[bb][chunk * 512]);
      gload_lds16(Bm + (size_t)(bN + chunk * 16 + srow) * ld + k0 + scol, &lb[bb][chunk * 512]);
    }
  };

  stage(0, 0);
  asm volatile("s_waitcnt vmcnt(0)" ::: "memory");
  __syncthreads();
  for (int kt = 0; kt < nk; ++kt) {
    const int bb = kt & 1;
    if (kt + 1 < nk) stage(kt + 1, bb ^ 1);
    bf16x8 af[4], bfr[4];
#pragma unroll
    for (int m = 0; m < 4; ++m)
      af[m] = *(const bf16x8*)(&la[bb][(wr * 64 + m * 16 + ar) * 32 + ak]);
#pragma unroll
    for (int n = 0; n < 4; ++n)
      bfr[n] = *(const bf16x8*)(&lb[bb][(wc * 64 + n * 16 + ar) * 32 + ak]);
#pragma unroll
    for (int m = 0; m < 4; ++m)
#pragma unroll
      for (int n = 0; n < 4; ++n)
        acc[m][n] = __builtin_amdgcn_mfma_f32_16x16x32_bf16(af[m], bfr[n], acc[m][n], 0, 0, 0);
    asm volatile("s_waitcnt vmcnt(0)" ::: "memory");
    __syncthreads();
  }
#pragma unroll
  for (int m = 0; m < 4; ++m)
#pragma unroll
    for (int n = 0; n < 4; ++n)
#pragma unroll
      for (int r = 0; r < 4; ++r) {
        int gm = bM + wr * 64 + m * 16 + (lane >> 4) * 4 + r;
        int gn = bN + wc * 64 + n * 16 + (lane & 15);
        float val = acc[m][n][r] + bias[gn];
        if constexpr (MODE == 0) {
          int b = gm >> 11, s = gm & 2047, h = gn >> 6, d = gn & 63;
          ((short*)outp)[(((size_t)b * NH + h) * SS + s) * 64 + d] = f2bf(val);
        } else if constexpr (MODE == 1) {
          int b = gm >> 11, s = gm & 2047, h = gn >> 6, d = gn & 63;
          ((short*)outp)[(((size_t)b * NH + h) * 64 + d) * SS + s] = f2bf(val);
        } else {
          ((float*)outp)[(size_t)gm * N + gn] = val;
        }
      }
}

// ---------------- fused attention: logits + softmax + weights-write + PV ----------------
// One block = one (b,h) x one 256-row q-tile. 512 threads (8 waves, 4x2 grid).
// Two sweeps over K (QK^T recomputed in sweep 2). K and V tiles double-buffered;
// stage(t+1) issued before compute(t); one vmcnt(0) drain per tile after the PV
// phase so both load latency and W-store drain hide under compute.
// All LDS tiles XOR-swizzled (byte ^= (row&7)<<4) via pre-swizzled gload sources.
// Grid: x = (b,h) so all q-tiles of one head share an XCD L2 (K/V = 512KB resident).
__global__ __launch_bounds__(512, 2) void attn_k(
    const short* __restrict__ qh, const short* __restrict__ kh,
    const short* __restrict__ vhT, const float* __restrict__ mask,
    float* __restrict__ wout, short* __restrict__ concat) {
  __shared__ short lP[256 * 128];     // 64KB: Q staging, then P tile (bf16, swizzled)
  __shared__ short lK[2][128 * 64];   // 2x16KB
  __shared__ short lV[2][64 * 128];   // 2x16KB
  __shared__ float lmask[2048];       // 8KB (pre-scaled by -1e9*log2e)
  __shared__ float lrs[2][256];       // 2KB row sums
  const int tid = threadIdx.x, wid = tid >> 6, lane = tid & 63;
  const int wr = wid >> 1, wc = wid & 1;
  const int bh = blockIdx.x, b = bh >> 4, h = bh & 15;
  const int bM = blockIdx.y * 256;
  const short* Qb = qh + (size_t)bh * SS * 64 + (size_t)bM * 64;
  const short* Kb = kh + (size_t)bh * SS * 64;
  const short* Vb = vhT + (size_t)bh * 64 * SS;
  float* Wb = wout + (size_t)bh * SS * SS;

#pragma unroll
  for (int i = 0; i < 4; ++i)
    lmask[tid + i * 512] = mask[b * SS + tid + i * 512] * MSK2;

  auto stageK = [&](int kt, int bb) {
#pragma unroll
    for (int c = 0; c < 2; ++c) {
      int ob = c * 8192 + tid * 16;
      int row = ob >> 7, inrow = ob & 127;
      gload_lds16(Kb + (size_t)(kt * 128 + row) * 64 + ((inrow ^ ((row & 7) << 4)) >> 1),
                  (char*)lK[bb] + ob);
    }
  };
  auto stageV = [&](int kt, int bb) {
#pragma unroll
    for (int c = 0; c < 2; ++c) {
      int ob = c * 8192 + tid * 16;
      int row = ob >> 8, inrow = ob & 255;
      gload_lds16(Vb + (size_t)row * SS + kt * 128 + ((inrow ^ ((row & 7) << 4)) >> 1),
                  (char*)lV[bb] + ob);
    }
  };

  // stage Q tile [256][64] swizzled into lP, and K(0)
#pragma unroll
  for (int c = 0; c < 4; ++c) {
    int ob = c * 8192 + tid * 16;
    int row = ob >> 7, inrow = ob & 127;
    gload_lds16(Qb + row * 64 + ((inrow ^ ((row & 7) << 4)) >> 1), (char*)lP + ob);
  }
  stageK(0, 0);
  asm volatile("s_waitcnt vmcnt(0)" ::: "memory");
  __syncthreads();
  bf16x8 af[4][2];
#pragma unroll
  for (int m = 0; m < 4; ++m)
#pragma unroll
    for (int kk = 0; kk < 2; ++kk) {
      int row = wr * 64 + m * 16 + (lane & 15);
      int kb = (kk * 32 + (lane >> 4) * 8) * 2;
      af[m][kk] = *(const bf16x8*)((const char*)lP + row * 128 + (kb ^ ((row & 7) << 4)));
    }
  __syncthreads();  // all waves done reading Q from lP before sweep-2 reuses it

  // ---- sweep 1: row sums of exp2(logit*SCL2 + maskterm) ----
  float ps[4][4];
#pragma unroll
  for (int m = 0; m < 4; ++m)
#pragma unroll
    for (int r = 0; r < 4; ++r) ps[m][r] = 0.f;

  for (int kt = 0; kt < 16; ++kt) {
    const int bb = kt & 1;
    if (kt < 15) stageK(kt + 1, bb ^ 1);
    bf16x8 bfr[4][2];
#pragma unroll
    for (int n = 0; n < 4; ++n)
#pragma unroll
      for (int kk = 0; kk < 2; ++kk) {
        int row = wc * 64 + n * 16 + (lane & 15);
        int kb = (kk * 32 + (lane >> 4) * 8) * 2;
        bfr[n][kk] = *(const bf16x8*)((const char*)lK[bb] + row * 128 + (kb ^ ((row & 7) << 4)));
      }
#pragma unroll
    for (int n = 0; n < 4; ++n) {
      float mv = lmask[kt * 128 + wc * 64 + n * 16 + (lane & 15)];
#pragma unroll
      for (int m = 0; m < 4; ++m) {
        f32x4 a = (f32x4){0.f, 0.f, 0.f, 0.f};
        a = __builtin_amdgcn_mfma_f32_16x16x32_bf16(af[m][0], bfr[n][0], a, 0, 0, 0);
        a = __builtin_amdgcn_mfma_f32_16x16x32_bf16(af[m][1], bfr[n][1], a, 0, 0, 0);
#pragma unroll
        for (int r = 0; r < 4; ++r) ps[m][r] += exp2f(a[r] * SCL2 + mv);
      }
    }
    asm volatile("s_waitcnt vmcnt(0)" ::: "memory");
    __syncthreads();
  }
  // reduce over the 16 lanes holding one row's 16 cols
#pragma unroll
  for (int m = 0; m < 4; ++m)
#pragma unroll
    for (int r = 0; r < 4; ++r) {
      float s = ps[m][r];
      s += __shfl_xor(s, 1, 64);
      s += __shfl_xor(s, 2, 64);
      s += __shfl_xor(s, 4, 64);
      s += __shfl_xor(s, 8, 64);
      ps[m][r] = s;
    }
  if ((lane & 15) == 0) {
#pragma unroll
    for (int m = 0; m < 4; ++m)
#pragma unroll
      for (int r = 0; r < 4; ++r)
        lrs[wc][wr * 64 + m * 16 + (lane >> 4) * 4 + r] = ps[m][r];
  }
  // issue sweep-2 prologue staging now; latency hides under lrs barrier + inv calc
  stageK(0, 0);
  stageV(0, 0);
  __syncthreads();  // lrs visible
  float inv[4][4];
#pragma unroll
  for (int m = 0; m < 4; ++m)
#pragma unroll
    for (int r = 0; r < 4; ++r) {
      int row = wr * 64 + m * 16 + (lane >> 4) * 4 + r;
      inv[m][r] = 1.f / (lrs[0][row] + lrs[1][row]);
    }
  asm volatile("s_waitcnt vmcnt(0)" ::: "memory");
  __syncthreads();

  // ---- sweep 2: recompute logits, write weights, PV accumulate ----
  f32x4 pacc[4][2];
#pragma unroll
  for (int m = 0; m < 4; ++m)
#pragma unroll
    for (int n = 0; n < 2; ++n) pacc[m][n] = (f32x4){0.f, 0.f, 0.f, 0.f};

  for (int kt = 0; kt < 16; ++kt) {
    const int bb = kt & 1;
    bf16x8 bfr[4][2];
#pragma unroll
    for (int n = 0; n < 4; ++n)
#pragma unroll
      for (int kk = 0; kk < 2; ++kk) {
        int row = wc * 64 + n * 16 + (lane & 15);
        int kb = (kk * 32 + (lane >> 4) * 8) * 2;
        bfr[n][kk] = *(const bf16x8*)((const char*)lK[bb] + row * 128 + (kb ^ ((row & 7) << 4)));
      }
    if (kt < 15) {  // issue loads before the store-heavy phase: loads older than stores
      stageK(kt + 1, bb ^ 1);
      stageV(kt + 1, bb ^ 1);
    }
#pragma unroll
    for (int n = 0; n < 4; ++n) {
      int col = wc * 64 + n * 16 + (lane & 15);
      float mv = lmask[kt * 128 + col];
#pragma unroll
      for (int m = 0; m < 4; ++m) {
        f32x4 a = (f32x4){0.f, 0.f, 0.f, 0.f};
        a = __builtin_amdgcn_mfma_f32_16x16x32_bf16(af[m][0], bfr[n][0], a, 0, 0, 0);
        a = __builtin_amdgcn_mfma_f32_16x16x32_bf16(af[m][1], bfr[n][1], a, 0, 0, 0);
#pragma unroll
        for (int r = 0; r < 4; ++r) {
          int prow = wr * 64 + m * 16 + (lane >> 4) * 4 + r;
          float w = exp2f(a[r] * SCL2 + mv) * inv[m][r];
          Wb[(size_t)(bM + prow) * SS + kt * 128 + col] = w;
          *(short*)((char*)lP + prow * 256 + ((col * 2) ^ ((prow & 7) << 4))) = f2bf(w);
        }
      }
    }
    __syncthreads();  // lP ready
    // PV: out[q][d] += P[q][k] * V^T[d][k]
#pragma unroll
    for (int kk = 0; kk < 4; ++kk) {
      bf16x8 pa[4], bv[2];
      int kb = (kk * 32 + (lane >> 4) * 8) * 2;
#pragma unroll
      for (int m = 0; m < 4; ++m) {
        int row = wr * 64 + m * 16 + (lane & 15);
        pa[m] = *(const bf16x8*)((const char*)lP + row * 256 + (kb ^ ((row & 7) << 4)));
      }
#pragma unroll
      for (int n = 0; n < 2; ++n) {
        int d = wc * 32 + n * 16 + (lane & 15);
        bv[n] = *(const bf16x8*)((const char*)lV[bb] + d * 256 + (kb ^ ((d & 7) << 4)));
      }
#pragma unroll
      for (int m = 0; m < 4; ++m)
#pragma unroll
        for (int n = 0; n < 2; ++n)
          pacc[m][n] = __builtin_amdgcn_mfma_f32_16x16x32_bf16(pa[m], bv[n], pacc[m][n], 0, 0, 0);
    }
    asm volatile("s_waitcnt vmcnt(0)" ::: "memory");  // drain loads(t+1) (+stores, head-started)
    __syncthreads();
  }
  // epilogue: attn (concat layout) bf16
#pragma unroll
  for (int m = 0; m < 4; ++m)
#pragma unroll
    for (int n = 0; n < 2; ++n)
#pragma unroll
      for (int r = 0; r < 4; ++r) {
        int s = bM + wr * 64 + m * 16 + (lane >> 4) * 4 + r;
        int d = wc * 32 + n * 16 + (lane & 15);
        concat[((size_t)(b * SS + s)) * DDim + h * 64 + d] = f2bf(pacc[m][n][r]);
      }
}

extern "C" void kernel_launch(void* const* d_in, const int* in_sizes, int n_in,
                              void* d_out, int out_size, void* d_ws, size_t ws_size,
                              hipStream_t stream) {
  const float* q = (const float*)d_in[0];
  const float* k = (const float*)d_in[1];
  const float* v = (const float*)d_in[2];
  const float* mask = (const float*)d_in[3];
  const float* wq_w = (const float*)d_in[4];
  const float* wq_b = (const float*)d_in[5];
  const float* wk_w = (const float*)d_in[6];
  const float* wk_b = (const float*)d_in[7];
  const float* wv_w = (const float*)d_in[8];
  const float* wv_b = (const float*)d_in[9];
  const float* wo_w = (const float*)d_in[10];
  const float* wo_b = (const float*)d_in[11];

  short* qb = (short*)d_ws;
  short* kb = qb + BSD;
  short* vb = kb + BSD;
  short* wqb = vb + BSD;
  short* wkb = wqb + DDn;
  short* wvb = wkb + DDn;
  short* wob = wvb + DDn;
  short* qh = wob + DDn;
  short* kh = qh + BSD;
  short* vhT = kh + BSD;
  short* concat = vhT + BSD;

  float* out0 = (float*)d_out;
  float* wts = out0 + BSD;  // [B,H,S,S] fp32

  const int n8_bsd = (int)(BSD / 8), n8_dd = (int)(DDn / 8);
  cvt_k<<<n8_bsd / 256, 256, 0, stream>>>(q, qb, n8_bsd);
  cvt_k<<<n8_bsd / 256, 256, 0, stream>>>(k, kb, n8_bsd);
  cvt_k<<<n8_bsd / 256, 256, 0, stream>>>(v, vb, n8_bsd);
  cvt_k<<<n8_dd / 256, 256, 0, stream>>>(wq_w, wqb, n8_dd);
  cvt_k<<<n8_dd / 256, 256, 0, stream>>>(wk_w, wkb, n8_dd);
  cvt_k<<<n8_dd / 256, 256, 0, stream>>>(wv_w, wvb, n8_dd);
  cvt_k<<<n8_dd / 256, 256, 0, stream>>>(wo_w, wob, n8_dd);

  dim3 gproj(DDim / 128, (NB * SS) / 128);  // (8, 32)
  gemm128<0><<<gproj, 256, 0, stream>>>(qb, wqb, wq_b, qh, DDim, DDim, DDim / 32);
  gemm128<0><<<gproj, 256, 0, stream>>>(kb, wkb, wk_b, kh, DDim, DDim, DDim / 32);
  gemm128<1><<<gproj, 256, 0, stream>>>(vb, wvb, wv_b, vhT, DDim, DDim, DDim / 32);

  dim3 gattn(NB * NH, SS / 256);  // (32, 8): x=(b,h) so one head's K/V stays on one XCD
  attn_k<<<gattn, 512, 0, stream>>>(qh, kh, vhT, mask, wts, concat);

  gemm128<2><<<gproj, 256, 0, stream>>>(concat, wob, wo_b, (void*)out0, DDim, DDim, DDim / 32);
}

// Round 5
// 315.522 us; speedup vs baseline: 1.1905x; 1.1905x over previous
//
#include <hip/hip_runtime.h>
#include <stdint.h>
#include <stddef.h>

static constexpr int NB = 2;       // batch
static constexpr int SS = 2048;    // seq
static constexpr int DDim = 1024;  // model dim
static constexpr int NH = 16;      // heads
static constexpr size_t BSD = (size_t)NB * SS * DDim;  // 4194304
static constexpr size_t DDn = (size_t)DDim * DDim;     // 1048576

typedef __attribute__((ext_vector_type(4))) float f32x4;
typedef __attribute__((ext_vector_type(8))) short bf16x8;

// exp2-folded constants: softmax uses exp2f(logit*SCL2 + mask*MSK2)
static constexpr float SCL2 = 0.125f * 1.4426950408889634f;
static constexpr float MSK2 = -1.4426950408889634e9f;

__device__ __forceinline__ short f2bf(float f) {
  union { float f; unsigned u; } v; v.f = f;
  unsigned r = v.u + 0x7FFFu + ((v.u >> 16) & 1u);
  return (short)(r >> 16);
}

__device__ __forceinline__ void gload_lds16(const void* src, void* dst) {
  __builtin_amdgcn_global_load_lds(
      (const __attribute__((address_space(1))) void*)src,
      (__attribute__((address_space(3))) void*)dst, 16, 0, 0);
}

// ---------------- fp32 -> bf16 convert: 4 weight matrices, one launch ----------------
__global__ void cvtw_k(const float* __restrict__ w0, const float* __restrict__ w1,
                       const float* __restrict__ w2, const float* __restrict__ w3,
                       short* __restrict__ out) {
  int i = blockIdx.x * 256 + threadIdx.x;          // i in [0, 4*DDn/8)
  int mat = i >> 17;                               // DDn/8 = 2^17
  const float* src = mat == 0 ? w0 : mat == 1 ? w1 : mat == 2 ? w2 : w3;
  const f32x4* p = (const f32x4*)src + (size_t)(i & 131071) * 2;
  f32x4 a = p[0], c = p[1];
  bf16x8 o;
  o[0] = f2bf(a[0]); o[1] = f2bf(a[1]); o[2] = f2bf(a[2]); o[3] = f2bf(a[3]);
  o[4] = f2bf(c[0]); o[5] = f2bf(c[1]); o[6] = f2bf(c[2]); o[7] = f2bf(c[3]);
  ((bf16x8*)out)[i] = o;
}

// ---------------- fp32 -> bf16 convert: q,k,v, one launch ----------------
__global__ void cvt3_k(const float* __restrict__ t0, const float* __restrict__ t1,
                       const float* __restrict__ t2, short* __restrict__ out) {
  int i = blockIdx.x * 256 + threadIdx.x;          // i in [0, 3*BSD/8)
  int mat = i >> 19;                               // BSD/8 = 2^19
  const float* src = mat == 0 ? t0 : mat == 1 ? t1 : t2;
  const f32x4* p = (const f32x4*)src + (size_t)(i & 524287) * 2;
  f32x4 a = p[0], c = p[1];
  bf16x8 o;
  o[0] = f2bf(a[0]); o[1] = f2bf(a[1]); o[2] = f2bf(a[2]); o[3] = f2bf(a[3]);
  o[4] = f2bf(c[0]); o[5] = f2bf(c[1]); o[6] = f2bf(c[2]); o[7] = f2bf(c[3]);
  ((bf16x8*)out)[i] = o;
}

// ---------------- all-3 projections, one launch (R3-proven dbuf GEMM body) ----------------
// grid (8, 32, 3): z selects (qb,wq)->qh, (kb,wk)->kh, (vb,wv)->vhT (block-uniform).
__global__ __launch_bounds__(256, 2) void proj3_k(
    const short* __restrict__ Acat, const short* __restrict__ Bcat,
    const float* __restrict__ bq, const float* __restrict__ bk, const float* __restrict__ bv,
    short* __restrict__ qh, short* __restrict__ kh, short* __restrict__ vhT) {
  __shared__ short la[2][4096], lb[2][4096];
  const int tid = threadIdx.x, wid = tid >> 6, lane = tid & 63;
  const int proj = blockIdx.z;
  const short* A = Acat + (size_t)proj * BSD;
  const short* Bm = Bcat + (size_t)proj * DDn;
  const float* bias = proj == 0 ? bq : proj == 1 ? bk : bv;
  const int bM = blockIdx.y * 128, bN = blockIdx.x * 128;
  const int ar = lane & 15, ak = (lane >> 4) * 8;
  const int srow = lane >> 2, scol = (lane & 3) * 8;
  const int wr = wid >> 1, wc = wid & 1;
  f32x4 acc[4][4];
#pragma unroll
  for (int m = 0; m < 4; ++m)
#pragma unroll
    for (int n = 0; n < 4; ++n) acc[m][n] = (f32x4){0.f, 0.f, 0.f, 0.f};

  auto stage = [&](int kt, int bb) {
    const int k0 = kt * 32;
#pragma unroll
    for (int c = 0; c < 2; ++c) {
      int chunk = c * 4 + wid;
      gload_lds16(A + (size_t)(bM + chunk * 16 + srow) * DDim + k0 + scol, &la[bb][chunk * 512]);
      gload_lds16(Bm + (size_t)(bN + chunk * 16 + srow) * DDim + k0 + scol, &lb[bb][chunk * 512]);
    }
  };

  stage(0, 0);
  asm volatile("s_waitcnt vmcnt(0)" ::: "memory");
  __syncthreads();
  for (int kt = 0; kt < 32; ++kt) {
    const int bb = kt & 1;
    if (kt < 31) stage(kt + 1, bb ^ 1);
    bf16x8 af[4], bfr[4];
#pragma unroll
    for (int m = 0; m < 4; ++m)
      af[m] = *(const bf16x8*)(&la[bb][(wr * 64 + m * 16 + ar) * 32 + ak]);
#pragma unroll
    for (int n = 0; n < 4; ++n)
      bfr[n] = *(const bf16x8*)(&lb[bb][(wc * 64 + n * 16 + ar) * 32 + ak]);
#pragma unroll
    for (int m = 0; m < 4; ++m)
#pragma unroll
      for (int n = 0; n < 4; ++n)
        acc[m][n] = __builtin_amdgcn_mfma_f32_16x16x32_bf16(af[m], bfr[n], acc[m][n], 0, 0, 0);
    asm volatile("s_waitcnt vmcnt(0)" ::: "memory");
    __syncthreads();
  }
#pragma unroll
  for (int m = 0; m < 4; ++m)
#pragma unroll
    for (int n = 0; n < 4; ++n)
#pragma unroll
      for (int r = 0; r < 4; ++r) {
        int gm = bM + wr * 64 + m * 16 + (lane >> 4) * 4 + r;
        int gn = bN + wc * 64 + n * 16 + (lane & 15);
        float val = acc[m][n][r] + bias[gn];
        int b = gm >> 11, s = gm & 2047, h = gn >> 6, d = gn & 63;
        if (proj == 2)
          vhT[(((size_t)b * NH + h) * 64 + d) * SS + s] = f2bf(val);
        else {
          short* o = proj == 0 ? qh : kh;
          o[(((size_t)b * NH + h) * SS + s) * 64 + d] = f2bf(val);
        }
      }
}

// ---------------- output projection (R3-proven dbuf GEMM body, fp32 out) ----------------
__global__ __launch_bounds__(256, 2) void outproj_k(
    const short* __restrict__ A, const short* __restrict__ Bm,
    const float* __restrict__ bias, float* __restrict__ outp) {
  __shared__ short la[2][4096], lb[2][4096];
  const int tid = threadIdx.x, wid = tid >> 6, lane = tid & 63;
  const int bM = blockIdx.y * 128, bN = blockIdx.x * 128;
  const int ar = lane & 15, ak = (lane >> 4) * 8;
  const int srow = lane >> 2, scol = (lane & 3) * 8;
  const int wr = wid >> 1, wc = wid & 1;
  f32x4 acc[4][4];
#pragma unroll
  for (int m = 0; m < 4; ++m)
#pragma unroll
    for (int n = 0; n < 4; ++n) acc[m][n] = (f32x4){0.f, 0.f, 0.f, 0.f};

  auto stage = [&](int kt, int bb) {
    const int k0 = kt * 32;
#pragma unroll
    for (int c = 0; c < 2; ++c) {
      int chunk = c * 4 + wid;
      gload_lds16(A + (size_t)(bM + chunk * 16 + srow) * DDim + k0 + scol, &la[bb][chunk * 512]);
      gload_lds16(Bm + (size_t)(bN + chunk * 16 + srow) * DDim + k0 + scol, &lb[bb][chunk * 512]);
    }
  };

  stage(0, 0);
  asm volatile("s_waitcnt vmcnt(0)" ::: "memory");
  __syncthreads();
  for (int kt = 0; kt < 32; ++kt) {
    const int bb = kt & 1;
    if (kt < 31) stage(kt + 1, bb ^ 1);
    bf16x8 af[4], bfr[4];
#pragma unroll
    for (int m = 0; m < 4; ++m)
      af[m] = *(const bf16x8*)(&la[bb][(wr * 64 + m * 16 + ar) * 32 + ak]);
#pragma unroll
    for (int n = 0; n < 4; ++n)
      bfr[n] = *(const bf16x8*)(&lb[bb][(wc * 64 + n * 16 + ar) * 32 + ak]);
#pragma unroll
    for (int m = 0; m < 4; ++m)
#pragma unroll
      for (int n = 0; n < 4; ++n)
        acc[m][n] = __builtin_amdgcn_mfma_f32_16x16x32_bf16(af[m], bfr[n], acc[m][n], 0, 0, 0);
    asm volatile("s_waitcnt vmcnt(0)" ::: "memory");
    __syncthreads();
  }
#pragma unroll
  for (int m = 0; m < 4; ++m)
#pragma unroll
    for (int n = 0; n < 4; ++n)
#pragma unroll
      for (int r = 0; r < 4; ++r) {
        int gm = bM + wr * 64 + m * 16 + (lane >> 4) * 4 + r;
        int gn = bN + wc * 64 + n * 16 + (lane & 15);
        outp[(size_t)gm * DDim + gn] = acc[m][n][r] + bias[gn];
      }
}

// ---------------- fused attention (R2-proven structure): logits+softmax+W-write+PV ----------------
// One block = one (b,h) x one 128-row q-tile, 256 threads, ~73KB LDS -> 2 blocks/CU
// (inter-block overlap hides the per-tile vmcnt(0)+barrier drains; m114).
__global__ __launch_bounds__(256, 2) void attn_k(
    const short* __restrict__ qh, const short* __restrict__ kh,
    const short* __restrict__ vhT, const float* __restrict__ mask,
    float* __restrict__ wout, short* __restrict__ concat) {
  __shared__ short lP[128 * 128];  // Q staging, then P tile (bf16, swizzled)
  __shared__ short lK[128 * 64];   // K tile (swizzled)
  __shared__ short lV[64 * 128];   // V^T tile (swizzled)
  __shared__ float lmask[2048];
  __shared__ float lrs[2][128];
  const int tid = threadIdx.x, wid = tid >> 6, lane = tid & 63;
  const int wr = wid >> 1, wc = wid & 1;
  const int bh = blockIdx.y, b = bh >> 4, h = bh & 15;
  const int bM = blockIdx.x * 128;
  const short* Qb = qh + (size_t)bh * SS * 64 + (size_t)bM * 64;
  const short* Kb = kh + (size_t)bh * SS * 64;
  const short* Vb = vhT + (size_t)bh * 64 * SS;
  float* Wb = wout + (size_t)bh * SS * SS;

#pragma unroll
  for (int i = 0; i < 8; ++i)
    lmask[tid + i * 256] = mask[b * SS + tid + i * 256] * MSK2;

  // stage Q tile [128][64] swizzled into lP
#pragma unroll
  for (int c = 0; c < 4; ++c) {
    int ob = c * 4096 + tid * 16;
    int row = ob >> 7, inrow = ob & 127;
    gload_lds16(Qb + row * 64 + ((inrow ^ ((row & 7) << 4)) >> 1), (char*)lP + ob);
  }
  asm volatile("s_waitcnt vmcnt(0)" ::: "memory");
  __syncthreads();
  bf16x8 af[4][2];
#pragma unroll
  for (int m = 0; m < 4; ++m)
#pragma unroll
    for (int kk = 0; kk < 2; ++kk) {
      int row = wr * 64 + m * 16 + (lane & 15);
      int kb = (kk * 32 + (lane >> 4) * 8) * 2;
      af[m][kk] = *(const bf16x8*)((const char*)lP + row * 128 + (kb ^ ((row & 7) << 4)));
    }

  // ---- sweep 1: row sums of exp2(logit*SCL2 + maskterm) ----
  float ps[4][4];
#pragma unroll
  for (int m = 0; m < 4; ++m)
#pragma unroll
    for (int r = 0; r < 4; ++r) ps[m][r] = 0.f;

  for (int kt = 0; kt < 16; ++kt) {
    __syncthreads();
#pragma unroll
    for (int c = 0; c < 4; ++c) {
      int ob = c * 4096 + tid * 16;
      int row = ob >> 7, inrow = ob & 127;
      gload_lds16(Kb + (size_t)(kt * 128 + row) * 64 + ((inrow ^ ((row & 7) << 4)) >> 1),
                  (char*)lK + ob);
    }
    asm volatile("s_waitcnt vmcnt(0)" ::: "memory");
    __syncthreads();
    bf16x8 bfr[4][2];
#pragma unroll
    for (int n = 0; n < 4; ++n)
#pragma unroll
      for (int kk = 0; kk < 2; ++kk) {
        int row = wc * 64 + n * 16 + (lane & 15);
        int kb = (kk * 32 + (lane >> 4) * 8) * 2;
        bfr[n][kk] = *(const bf16x8*)((const char*)lK + row * 128 + (kb ^ ((row & 7) << 4)));
      }
#pragma unroll
    for (int n = 0; n < 4; ++n) {
      float mv = lmask[kt * 128 + wc * 64 + n * 16 + (lane & 15)];
#pragma unroll
      for (int m = 0; m < 4; ++m) {
        f32x4 a = (f32x4){0.f, 0.f, 0.f, 0.f};
        a = __builtin_amdgcn_mfma_f32_16x16x32_bf16(af[m][0], bfr[n][0], a, 0, 0, 0);
        a = __builtin_amdgcn_mfma_f32_16x16x32_bf16(af[m][1], bfr[n][1], a, 0, 0, 0);
#pragma unroll
        for (int r = 0; r < 4; ++r) ps[m][r] += exp2f(a[r] * SCL2 + mv);
      }
    }
  }
  // reduce over the 16 lanes holding one row's 16 cols
#pragma unroll
  for (int m = 0; m < 4; ++m)
#pragma unroll
    for (int r = 0; r < 4; ++r) {
      float s = ps[m][r];
      s += __shfl_xor(s, 1, 64);
      s += __shfl_xor(s, 2, 64);
      s += __shfl_xor(s, 4, 64);
      s += __shfl_xor(s, 8, 64);
      ps[m][r] = s;
    }
  if ((lane & 15) == 0) {
#pragma unroll
    for (int m = 0; m < 4; ++m)
#pragma unroll
      for (int r = 0; r < 4; ++r)
        lrs[wc][wr * 64 + m * 16 + (lane >> 4) * 4 + r] = ps[m][r];
  }
  __syncthreads();
  float inv[4][4];
#pragma unroll
  for (int m = 0; m < 4; ++m)
#pragma unroll
    for (int r = 0; r < 4; ++r) {
      int row = wr * 64 + m * 16 + (lane >> 4) * 4 + r;
      inv[m][r] = 1.f / (lrs[0][row] + lrs[1][row]);
    }

  // ---- sweep 2: recompute logits, write weights, PV accumulate ----
  f32x4 pacc[4][2];
#pragma unroll
  for (int m = 0; m < 4; ++m)
#pragma unroll
    for (int n = 0; n < 2; ++n) pacc[m][n] = (f32x4){0.f, 0.f, 0.f, 0.f};

  for (int kt = 0; kt < 16; ++kt) {
    __syncthreads();
#pragma unroll
    for (int c = 0; c < 4; ++c) {
      int ob = c * 4096 + tid * 16;
      int row = ob >> 7, inrow = ob & 127;
      gload_lds16(Kb + (size_t)(kt * 128 + row) * 64 + ((inrow ^ ((row & 7) << 4)) >> 1),
                  (char*)lK + ob);
    }
#pragma unroll
    for (int c = 0; c < 4; ++c) {
      int ob = c * 4096 + tid * 16;
      int row = ob >> 8, inrow = ob & 255;
      gload_lds16(Vb + (size_t)row * SS + kt * 128 + ((inrow ^ ((row & 7) << 4)) >> 1),
                  (char*)lV + ob);
    }
    asm volatile("s_waitcnt vmcnt(0)" ::: "memory");
    __syncthreads();
    bf16x8 bfr[4][2];
#pragma unroll
    for (int n = 0; n < 4; ++n)
#pragma unroll
      for (int kk = 0; kk < 2; ++kk) {
        int row = wc * 64 + n * 16 + (lane & 15);
        int kb = (kk * 32 + (lane >> 4) * 8) * 2;
        bfr[n][kk] = *(const bf16x8*)((const char*)lK + row * 128 + (kb ^ ((row & 7) << 4)));
      }
#pragma unroll
    for (int n = 0; n < 4; ++n) {
      int col = wc * 64 + n * 16 + (lane & 15);
      float mv = lmask[kt * 128 + col];
#pragma unroll
      for (int m = 0; m < 4; ++m) {
        f32x4 a = (f32x4){0.f, 0.f, 0.f, 0.f};
        a = __builtin_amdgcn_mfma_f32_16x16x32_bf16(af[m][0], bfr[n][0], a, 0, 0, 0);
        a = __builtin_amdgcn_mfma_f32_16x16x32_bf16(af[m][1], bfr[n][1], a, 0, 0, 0);
#pragma unroll
        for (int r = 0; r < 4; ++r) {
          int prow = wr * 64 + m * 16 + (lane >> 4) * 4 + r;
          float w = exp2f(a[r] * SCL2 + mv) * inv[m][r];
          Wb[(size_t)(bM + prow) * SS + kt * 128 + col] = w;
          *(short*)((char*)lP + prow * 256 + ((col * 2) ^ ((prow & 7) << 4))) = f2bf(w);
        }
      }
    }
    __syncthreads();  // lP ready
    // PV: out[q][d] += P[q][k] * V^T[d][k]
#pragma unroll
    for (int kk = 0; kk < 4; ++kk) {
      bf16x8 pa[4], bv[2];
      int kb = (kk * 32 + (lane >> 4) * 8) * 2;
#pragma unroll
      for (int m = 0; m < 4; ++m) {
        int row = wr * 64 + m * 16 + (lane & 15);
        pa[m] = *(const bf16x8*)((const char*)lP + row * 256 + (kb ^ ((row & 7) << 4)));
      }
#pragma unroll
      for (int n = 0; n < 2; ++n) {
        int d = wc * 32 + n * 16 + (lane & 15);
        bv[n] = *(const bf16x8*)((const char*)lV + d * 256 + (kb ^ ((d & 7) << 4)));
      }
#pragma unroll
      for (int m = 0; m < 4; ++m)
#pragma unroll
        for (int n = 0; n < 2; ++n)
          pacc[m][n] = __builtin_amdgcn_mfma_f32_16x16x32_bf16(pa[m], bv[n], pacc[m][n], 0, 0, 0);
    }
  }
  // epilogue: attn (concat layout) bf16
#pragma unroll
  for (int m = 0; m < 4; ++m)
#pragma unroll
    for (int n = 0; n < 2; ++n)
#pragma unroll
      for (int r = 0; r < 4; ++r) {
        int s = bM + wr * 64 + m * 16 + (lane >> 4) * 4 + r;
        int d = wc * 32 + n * 16 + (lane & 15);
        concat[((size_t)(b * SS + s)) * DDim + h * 64 + d] = f2bf(pacc[m][n][r]);
      }
}

extern "C" void kernel_launch(void* const* d_in, const int* in_sizes, int n_in,
                              void* d_out, int out_size, void* d_ws, size_t ws_size,
                              hipStream_t stream) {
  const float* q = (const float*)d_in[0];
  const float* k = (const float*)d_in[1];
  const float* v = (const float*)d_in[2];
  const float* mask = (const float*)d_in[3];
  const float* wq_w = (const float*)d_in[4];
  const float* wq_b = (const float*)d_in[5];
  const float* wk_w = (const float*)d_in[6];
  const float* wk_b = (const float*)d_in[7];
  const float* wv_w = (const float*)d_in[8];
  const float* wv_b = (const float*)d_in[9];
  const float* wo_w = (const float*)d_in[10];
  const float* wo_b = (const float*)d_in[11];

  // ws layout (shorts)
  short* qb = (short*)d_ws;       // qb,kb,vb contiguous (Acat): 3*BSD
  short* wqb = qb + 3 * BSD;      // wq,wk,wv contiguous (Bcat): 3*DDn
  short* wob = wqb + 3 * DDn;     // DDn
  short* qh = wob + DDn;
  short* kh = qh + BSD;
  short* vhT = kh + BSD;
  short* concat = vhT + BSD;

  float* out0 = (float*)d_out;
  float* wts = out0 + BSD;  // [B,H,S,S] fp32

  cvtw_k<<<2048, 256, 0, stream>>>(wq_w, wk_w, wv_w, wo_w, wqb);
  cvt3_k<<<6144, 256, 0, stream>>>(q, k, v, qb);

  dim3 gproj(DDim / 128, (NB * SS) / 128, 3);  // (8, 32, 3)
  proj3_k<<<gproj, 256, 0, stream>>>(qb, wqb, wq_b, wk_b, wv_b, qh, kh, vhT);

  dim3 gattn(SS / 128, NB * NH);  // (16, 32)
  attn_k<<<gattn, 256, 0, stream>>>(qh, kh, vhT, mask, wts, concat);

  dim3 gout(DDim / 128, (NB * SS) / 128);  // (8, 32)
  outproj_k<<<gout, 256, 0, stream>>>(concat, wob, wo_b, out0);
}